// Round 7
// baseline (118.954 us; speedup 1.0000x reference)
//
#include <hip/hip_runtime.h>
#include <hip/hip_bf16.h>
#include <math.h>

// Problem constants: B=64, way=5, shot=1, D=640, H=W=5 (hw=25), nq=75, k=5
#define NB    64
#define WAY   5
#define DCH   640
#define HW    25
#define NQ    75
#define NBK   5
#define EPSN  1e-12f

#define NDG   (DCH / 8)                  // 80 d-groups
#define SCOLS 128                        // 125 support cols + 3 zero pads
#define CD    160                        // chunk depth (d per staged chunk)
#define NCHK  (DCH / CD)                 // 4 chunks
#define DGC   (CD / 8)                   // 20 d-groups per chunk
#define CFL   (CD * HW)                  // 4000 floats per chunk (1000 vec4)
#define CTS   132                        // ct row stride (128 + 4 pad)

typedef __attribute__((ext_vector_type(8)))  short  bf16x8;
typedef __attribute__((ext_vector_type(8)))  ushort u16x8;
typedef __attribute__((ext_vector_type(16))) float  f32x16;
typedef __attribute__((ext_vector_type(4)))  float  f32x4;

__device__ inline ushort f2bf(float f) {
    uint u = __float_as_uint(f);
    return (ushort)((u + 0x7FFFu + ((u >> 16) & 1u)) >> 16);   // RNE
}

// ---------------------------------------------------------------------------
// K1: per (b,way):
//   invs[bk*25+l]  = 1/||base[b,k,:,l]||
//   invsm[bk]      = 1/max(||mean_l base[b,k,:,:]||, eps)
//   sT[b][dg][k*25+l][e] = bf16(base[b,k,dg*8+e,l])   (MFMA-native A layout)
// ---------------------------------------------------------------------------
__global__ __launch_bounds__(256) void k_prep(const float* __restrict__ base,
                                              float* __restrict__ invs,
                                              float* __restrict__ invsm,
                                              ushort* __restrict__ sT)
{
    const int bk = blockIdx.x;                 // 0..319
    const int b  = bk / WAY;
    const int k  = bk - b * WAY;
    const float* src = base + (size_t)bk * (DCH * HW);
    __shared__ float lds[DCH * HW];
    __shared__ float red[256];
    const int tid = threadIdx.x;

    const f32x4* s4 = (const f32x4*)src;
    f32x4* l4 = (f32x4*)lds;
    for (int i = tid; i < (DCH * HW) / 4; i += 256)
        l4[i] = __builtin_nontemporal_load(s4 + i);
    __syncthreads();

    if (tid < HW) {
        float ss = 0.f;
        for (int d = 0; d < DCH; ++d) { float v = lds[d * HW + tid]; ss = fmaf(v, v, ss); }
        invs[bk * HW + tid] = rsqrtf(ss);      // ref: no eps on column norms
    }

    float ssq = 0.f;
    for (int d = tid; d < DCH; d += 256) {
        float s = 0.f;
        #pragma unroll
        for (int pp = 0; pp < HW; ++pp) s += lds[d * HW + pp];
        float m = s * (1.0f / HW);
        ssq = fmaf(m, m, ssq);
    }
    red[tid] = ssq;
    __syncthreads();
    for (int s = 128; s > 0; s >>= 1) {
        if (tid < s) red[tid] += red[tid + s];
        __syncthreads();
    }
    if (tid == 0) invsm[bk] = 1.0f / fmaxf(sqrtf(red[0]), EPSN);

    // transposed bf16 support write: [dg][scol][8]
    ushort* dstb = sT + (size_t)b * (NDG * SCOLS * 8);
    for (int t = tid; t < NDG * HW; t += 256) {
        const int dg = t / HW, l = t - dg * HW;
        u16x8 v;
        #pragma unroll
        for (int e = 0; e < 8; ++e) v[e] = f2bf(lds[(dg * 8 + e) * HW + l]);
        *(u16x8*)&dstb[((size_t)dg * SCOLS + k * HW + l) * 8] = v;
    }
    if (k == 0) {                              // zero pad scols 125..127
        const u16x8 z = (u16x8)(ushort)0;
        for (int t = tid; t < NDG * 3; t += 256) {
            const int dg = t / 3, sc = 125 + (t - dg * 3);
            *(u16x8*)&dstb[((size_t)dg * SCOLS + sc) * 8] = z;
        }
    }
}

// ---------------------------------------------------------------------------
// K2: block = ONE query (4800 blocks), 4 waves. Wave w owns scol-tile
// [32w..32w+31]; acc = 16 VGPR + 16 for redundant Gram -> high occupancy.
// Query chunk staged once per block: coalesced NT f32x4 -> bf16 transposed
// LDS [dg][32p][8]; B-frag = one contiguous conflict-free ds_read_b128.
// A-frags from sT (global, L2-hot). Epilogue via LDS (overlaying bq).
// ---------------------------------------------------------------------------
__global__ __launch_bounds__(256, 4) void k_fused(const float* __restrict__ query,
                                                  const ushort* __restrict__ sT,
                                                  const float* __restrict__ invs,
                                                  const float* __restrict__ invsm,
                                                  const float* __restrict__ r,
                                                  float* __restrict__ out)
{
    __shared__ ushort s_bq[2][DGC * 32 * 8];   // 20480 B, double-buffered B tiles
    __shared__ float invs_l[SCOLS];
    __shared__ float invsm_l[WAY];

    const int tid  = threadIdx.x;
    const int wid  = tid >> 6;
    const int lane = tid & 63;
    const int p    = lane & 31;
    const int hi   = lane >> 5;

    // XCD-chunked swizzle: 4800 = 8 * 600, bijective.
    const int wk = (blockIdx.x & 7) * 600 + (blockIdx.x >> 3);
    const int b  = wk / NQ;
    const int q  = wk - b * NQ;

    if (tid < WAY * HW) invs_l[tid] = invs[b * WAY * HW + tid];
    if (tid >= WAY * HW && tid < SCOLS) invs_l[tid] = 0.f;
    if (tid < WAY)      invsm_l[tid] = invsm[b * WAY + tid];

    const float* qrow = query + (size_t)(b * NQ + q) * (DCH * HW);
    const ushort* sTb = sT + (size_t)b * (NDG * SCOLS * 8);

    f32x16 accT = {}, accG = {};
    f32x4 lA0 = {}, lA1 = {}, lA2 = {}, lA3 = {};
    f32x4 lB0 = {}, lB1 = {}, lB2 = {}, lB3 = {};

#define LOADQ(c, R0, R1, R2, R3)                                              \
    {                                                                         \
        const f32x4* s4_ = (const f32x4*)(qrow + (size_t)(c) * CFL);          \
        R0 = __builtin_nontemporal_load(s4_ + tid);                           \
        R1 = __builtin_nontemporal_load(s4_ + 256 + tid);                     \
        R2 = __builtin_nontemporal_load(s4_ + 512 + tid);                     \
        if (tid < 232) R3 = __builtin_nontemporal_load(s4_ + 768 + tid);      \
    }

    // bf16-convert + transpose one f32x4 into the bq tile
#define WR4(DST, SLOT, V)                                                     \
    {                                                                         \
        _Pragma("unroll")                                                     \
        for (int j = 0; j < 4; ++j) {                                         \
            const int flat = (SLOT) * 4 + j;                                  \
            const int d  = flat / 25;                                         \
            const int pp = flat - d * 25;                                     \
            (DST)[((d >> 3) * 32 + pp) * 8 + (d & 7)] = f2bf((V)[j]);         \
        }                                                                     \
    }

#define WRITEQ(BUF, R0, R1, R2, R3)                                           \
    {                                                                         \
        ushort* db_ = &s_bq[BUF][0];                                          \
        WR4(db_, tid, R0)                                                     \
        WR4(db_, 256 + tid, R1)                                               \
        WR4(db_, 512 + tid, R2)                                               \
        if (tid < 232) WR4(db_, 768 + tid, R3)                                \
    }

#define COMPUTE(BUF, C)                                                       \
    {                                                                         \
        _Pragma("unroll")                                                     \
        for (int ks = 0; ks < DGC / 2; ++ks) {                                \
            const int dgl = ks * 2 + hi;                                      \
            const bf16x8 bq = *(const bf16x8*)&s_bq[BUF][(dgl * 32 + p) * 8]; \
            const bf16x8 a  = *(const bf16x8*)(sTb +                          \
                ((size_t)((C) * DGC + dgl) * SCOLS + wid * 32 + p) * 8);      \
            accT = __builtin_amdgcn_mfma_f32_32x32x16_bf16(a,  bq, accT, 0, 0, 0); \
            accG = __builtin_amdgcn_mfma_f32_32x32x16_bf16(bq, bq, accG, 0, 0, 0); \
        }                                                                     \
    }

    LOADQ(0, lA0, lA1, lA2, lA3)
    // zero pad patch slots 25..31 of both buffers (never written by staging)
    for (int i = tid; i < 2 * DGC * 7; i += 256) {
        const int bu = i / (DGC * 7), r2 = i % (DGC * 7);
        const int dg = r2 / 7, s = r2 % 7;
        *(u16x8*)&s_bq[bu][((dg * 32) + 25 + s) * 8] = (u16x8)(ushort)0;
    }
    WRITEQ(0, lA0, lA1, lA2, lA3)
    __syncthreads();
    LOADQ(1, lB0, lB1, lB2, lB3)
    COMPUTE(0, 0)
    __syncthreads();
    LOADQ(2, lA0, lA1, lA2, lA3)
    WRITEQ(1, lB0, lB1, lB2, lB3)
    __syncthreads();
    COMPUTE(1, 1)
    __syncthreads();
    LOADQ(3, lB0, lB1, lB2, lB3)
    WRITEQ(0, lA0, lA1, lA2, lA3)
    __syncthreads();
    COMPUTE(0, 2)
    __syncthreads();
    WRITEQ(1, lB0, lB1, lB2, lB3)
    __syncthreads();
    COMPUTE(1, 3)

#undef LOADQ
#undef WR4
#undef WRITEQ
#undef COMPUTE

    // ---- per-wave register epilogue (before touching overlay LDS) ----
    // C/D layout: col = lane&31, row = (reg&3) + 8*(reg>>2) + 4*hi.
    const bool pok = p < HW;

    float diag = 0.f, qq = 0.f;
    #pragma unroll
    for (int rr = 0; rr < 16; ++rr) {
        const int rowb = (rr & 3) + 8 * (rr >> 2);
        const int row = rowb + 4 * hi;
        diag = (row == p) ? accG[rr] : diag;
        if (row < HW) qq += accG[rr];
    }
    if (!pok) qq = 0.f;
    #pragma unroll
    for (int o = 1; o < 64; o <<= 1) qq += __shfl_xor(qq, o);
    diag += __shfl_xor(diag, 32);
    const float invq = rsqrtf(diag);           // 1/||q_p|| (pad lanes unused)

    // raw per-scol column sums (sum over patches p) — reduce within 32-lane half
    float cs16[16];
    #pragma unroll
    for (int rr = 0; rr < 16; ++rr) {
        float tv = pok ? accT[rr] : 0.f;
        #pragma unroll
        for (int o = 1; o < 32; o <<= 1) tv += __shfl_xor(tv, o);
        cs16[rr] = tv;
    }

    __syncthreads();   // all waves done reading s_bq -> overlay becomes valid

    // ---- overlay region ----
    float* ct       = (float*)&s_bq[0][0];     // [25][CTS] scaled sims, 3300 f
    float* cs_lds   = ct + HW * CTS;           // [128] raw col sums
    float* tops_lds = cs_lds + SCOLS;          // [125] per-(way,p) top5 sums

    if (p == 0) {
        #pragma unroll
        for (int rr = 0; rr < 16; ++rr) {
            const int rowb = (rr & 3) + 8 * (rr >> 2);
            cs_lds[wid * 32 + rowb + 4 * hi] = cs16[rr];
        }
    }
    if (pok) {
        #pragma unroll
        for (int rr = 0; rr < 16; ++rr) {
            const int rowb = (rr & 3) + 8 * (rr >> 2);
            const int scol = wid * 32 + rowb + 4 * hi;
            ct[p * CTS + scol] = accT[rr] * invq * invs_l[scol];
        }
    }
    __syncthreads();

    if (tid < WAY * HW) {                       // tid = way*25 + p
        const int way = tid / HW, pp = tid - way * HW;
        const float* row = &ct[pp * CTS + way * HW];
        float t0 = -3.402823466e38f, t1 = t0, t2 = t0, t3 = t0, t4 = t0;
        #pragma unroll
        for (int j = 0; j < HW; ++j) {
            float x = row[j], a;
            a = fmaxf(t0, x); x = fminf(t0, x); t0 = a;
            a = fmaxf(t1, x); x = fminf(t1, x); t1 = a;
            a = fmaxf(t2, x); x = fminf(t2, x); t2 = a;
            a = fmaxf(t3, x); x = fminf(t3, x); t3 = a;
            a = fmaxf(t4, x); x = fminf(t4, x); t4 = a;
        }
        tops_lds[tid] = t0 + t1 + t2 + t3 + t4;
    }
    __syncthreads();

    if (tid < WAY) {
        float gsv = 0.f, dn = 0.f;
        #pragma unroll
        for (int j = 0; j < HW; ++j) {
            gsv += cs_lds[tid * HW + j];
            dn  += tops_lds[tid * HW + j];
        }
        const float invqm = 1.0f / fmaxf(sqrtf(qq) * (1.0f / HW), EPSN);
        out[(size_t)(b * NQ + q) * WAY + tid] =
            r[0] * gsv * (1.0f / 625.0f) * invqm * invsm_l[tid]
          + r[1] * dn * (1.0f / NBK);
    }
}

// ---------------------------------------------------------------------------
extern "C" void kernel_launch(void* const* d_in, const int* in_sizes, int n_in,
                              void* d_out, int out_size, void* d_ws, size_t ws_size,
                              hipStream_t stream)
{
    const float* base  = (const float*)d_in[0];
    const float* query = (const float*)d_in[1];
    const float* r     = (const float*)d_in[2];
    float* out = (float*)d_out;

    float* invs   = (float*)d_ws;                        // 320*25 floats
    float* invsm  = invs + NB * WAY * HW;                // 320 floats
    ushort* sT    = (ushort*)((float*)d_ws + 16384);     // 64 * 80*128*8 bf16 = 10 MB

    k_prep<<<NB * WAY, 256, 0, stream>>>(base, invs, invsm, sT);
    k_fused<<<NB * NQ, 256, 0, stream>>>(query, sT, invs, invsm, r, out);
}